// Round 3
// baseline (99.212 us; speedup 1.0000x reference)
//
#include <hip/hip_runtime.h>
#include <stdint.h>

typedef int   int4v   __attribute__((ext_vector_type(4)));
typedef float float4v __attribute__((ext_vector_type(4)));

static constexpr int DIM = 4096;          // N = IN = OUT
static constexpr int BM  = 256, BN = 256; // block tile
static constexpr int BK  = 128;           // K-step bytes (2 MFMA k-steps of K=64)
static constexpr int NKT = DIM / BK;      // 32

// ---------------- quantization kernels ----------------
__global__ __launch_bounds__(256) void quant_act_kernel(
    const float* __restrict__ x, const float* __restrict__ s_ptr,
    const int* __restrict__ zp_ptr, int* __restrict__ out, int n4) {
  const float s  = s_ptr[0];
  const int   zp = zp_ptr[0];
  int idx    = blockIdx.x * blockDim.x + threadIdx.x;
  int stride = gridDim.x * blockDim.x;
  for (int i = idx; i < n4; i += stride) {
    float4v v = reinterpret_cast<const float4v*>(x)[i];
    int packed = 0;
#pragma unroll
    for (int j = 0; j < 4; ++j) {
      int q = (int)rintf(v[j] / s) + zp;
      q = min(max(q, 0), 255);
      q -= zp;
      packed |= (q & 255) << (8 * j);
    }
    out[i] = packed;
  }
}

__global__ __launch_bounds__(256) void quant_wgt_kernel(
    const float* __restrict__ w, const float* __restrict__ ws,
    const int* __restrict__ wzp, int* __restrict__ out, int n4) {
  int idx    = blockIdx.x * blockDim.x + threadIdx.x;
  int stride = gridDim.x * blockDim.x;
  for (int i = idx; i < n4; i += stride) {
    const int row = i >> 10;
    const float s = ws[row];
    const int  zp = wzp[row];
    float4v v = reinterpret_cast<const float4v*>(w)[i];
    int packed = 0;
#pragma unroll
    for (int j = 0; j < 4; ++j) {
      int q = (int)rintf(v[j] / s) + zp;
      q = min(max(q, 0), 255);
      q -= zp;
      packed |= (q & 255) << (8 * j);
    }
    out[i] = packed;
  }
}

// ---------------- int8 GEMM: 256^2, 8 waves, 4-phase, dbuf, swizzle, counted vmcnt ----------------
// Pipeline: phase 4 of K-tile kt stages kt+2 into the CURRENT buffer (its reads
// finished by end of phase 3), then boundary waits vmcnt(8) -> those 8 loads
// remain in flight across the barrier; kt+1's loads (issued one full K-tile
// earlier) are the 8 oldest and are guaranteed landed. Never drains to 0 in
// the main loop (T4).

#define PHASE_MFMA(MH, NH)                                                    \
  __builtin_amdgcn_s_barrier();                                               \
  asm volatile("s_waitcnt lgkmcnt(0)" ::: "memory");                          \
  __builtin_amdgcn_s_setprio(1);                                              \
  _Pragma("unroll") for (int kk = 0; kk < 2; ++kk)                            \
  _Pragma("unroll") for (int m = 0; m < 4; ++m)                               \
  _Pragma("unroll") for (int n = 0; n < 2; ++n)                               \
      acc[(MH)*4 + m][(NH)*2 + n] = __builtin_amdgcn_mfma_i32_16x16x64_i8(    \
          af[m][kk], bf[(NH)*2 + n][kk], acc[(MH)*4 + m][(NH)*2 + n], 0,0,0); \
  __builtin_amdgcn_s_setprio(0);                                              \
  __builtin_amdgcn_s_barrier();

__global__ __launch_bounds__(512) void gemm_i8_8ph(
    const signed char* __restrict__ A, const signed char* __restrict__ B,
    const float* __restrict__ s_act, const float* __restrict__ w_scale,
    const float* __restrict__ bias, float* __restrict__ C) {
  extern __shared__ signed char smem[];  // 2 buffers x (A 32K + B 32K) = 128 KiB

  const int tid  = threadIdx.x;
  const int w    = tid >> 6;            // wave 0..7
  const int lane = tid & 63;
  const int wr = w >> 2, wc = w & 3;    // 2 x 4 wave grid; wave tile 128x64
  const int l15 = lane & 15, lhi = lane >> 4;
  const int swk = (l15 & 7) << 4;       // read-side XOR swizzle key ((row&7)<<4)

  const int srow = lane >> 3;                           // staging row within 8-row chunk
  const int scol = ((lane & 7) ^ (lane >> 3)) << 4;     // pre-swizzled global col

  // T1: XCD-aware swizzle (nwg = 256, 256 % 8 == 0 -> simple bijective form)
  const int bid = blockIdx.x;
  const int swz = (bid & 7) * 32 + (bid >> 3);
  const int tileM = (swz >> 4) * BM;
  const int tileN = (swz & 15) * BN;

  auto stageA = [&](int i, int ktn, signed char* aL) {
    const int c = 4 * w + i;
    const size_t g = (size_t)(tileM + c * 8 + srow) * DIM + (size_t)ktn * BK + scol;
    __builtin_amdgcn_global_load_lds(
        (const __attribute__((address_space(1))) void*)(A + g),
        (__attribute__((address_space(3))) void*)(aL + c * 1024), 16, 0, 0);
  };
  auto stageB = [&](int i, int ktn, signed char* bL) {
    const int c = 4 * w + i;
    const size_t g = (size_t)(tileN + c * 8 + srow) * DIM + (size_t)ktn * BK + scol;
    __builtin_amdgcn_global_load_lds(
        (const __attribute__((address_space(1))) void*)(B + g),
        (__attribute__((address_space(3))) void*)(bL + c * 1024), 16, 0, 0);
  };
  auto rdA = [&](const signed char* aL, int mh, int m, int kk) -> int4v {
    const int r = wr * 128 + (mh * 4 + m) * 16 + l15;
    return *(const int4v*)(aL + r * BK + ((kk * 64 + lhi * 16) ^ swk));
  };
  auto rdB = [&](const signed char* bL, int nidx, int kk) -> int4v {
    const int r = wc * 64 + nidx * 16 + l15;
    return *(const int4v*)(bL + r * BK + ((kk * 64 + lhi * 16) ^ swk));
  };

  int4v acc[8][4] = {};
  int4v af[4][2];
  int4v bf[4][2];

  // prologue: stage tile 0 -> buf0, tile 1 -> buf1; wait only for tile 0
  {
    signed char* a0 = smem;
    signed char* b0 = smem + 32768;
    signed char* a1 = smem + 65536;
    signed char* b1 = smem + 65536 + 32768;
#pragma unroll
    for (int i = 0; i < 4; ++i) { stageA(i, 0, a0); stageB(i, 0, b0); }
#pragma unroll
    for (int i = 0; i < 4; ++i) { stageA(i, 1, a1); stageB(i, 1, b1); }
  }
  asm volatile("s_waitcnt vmcnt(8)" ::: "memory");
  __builtin_amdgcn_s_barrier();

  for (int kt = 0; kt < NKT; ++kt) {
    signed char* aL = smem + (kt & 1) * 65536;
    signed char* bL = aL + 32768;

    // ---- phase 1: read A(mh0), B(n0..1); MFMA quadrant (0,0)
#pragma unroll
    for (int m = 0; m < 4; ++m) { af[m][0] = rdA(aL, 0, m, 0); af[m][1] = rdA(aL, 0, m, 1); }
#pragma unroll
    for (int n = 0; n < 2; ++n) { bf[n][0] = rdB(bL, n, 0); bf[n][1] = rdB(bL, n, 1); }
    PHASE_MFMA(0, 0)

    // ---- phase 2: read B(n2..3); MFMA quadrant (0,1)
#pragma unroll
    for (int n = 2; n < 4; ++n) { bf[n][0] = rdB(bL, n, 0); bf[n][1] = rdB(bL, n, 1); }
    PHASE_MFMA(0, 1)

    // ---- phase 3: read A(mh1); MFMA quadrant (1,0)
#pragma unroll
    for (int m = 0; m < 4; ++m) { af[m][0] = rdA(aL, 1, m, 0); af[m][1] = rdA(aL, 1, m, 1); }
    PHASE_MFMA(1, 0)

    // ---- phase 4: current buffer is dead (all its ds_reads drained by phase 3's
    // lgkmcnt+barrier) -> stage kt+2 into it; MFMA quadrant (1,1); counted wait.
    const bool st = (kt + 2 < NKT);
    if (st) {
#pragma unroll
      for (int i = 0; i < 4; ++i) { stageA(i, kt + 2, aL); stageB(i, kt + 2, bL); }
    }
    __builtin_amdgcn_s_setprio(1);
#pragma unroll
    for (int kk = 0; kk < 2; ++kk)
#pragma unroll
      for (int m = 0; m < 4; ++m)
#pragma unroll
        for (int n = 0; n < 2; ++n)
          acc[4 + m][2 + n] = __builtin_amdgcn_mfma_i32_16x16x64_i8(
              af[m][kk], bf[2 + n][kk], acc[4 + m][2 + n], 0, 0, 0);
    __builtin_amdgcn_s_setprio(0);
    if (st) {
      asm volatile("s_waitcnt vmcnt(8)" ::: "memory");  // kt+1 landed; kt+2 in flight
    } else {
      asm volatile("s_waitcnt vmcnt(0)" ::: "memory");  // tail (last 2 iters)
    }
    __builtin_amdgcn_s_barrier();
  }

  // ---- epilogue: C/D layout col=lane&15, row=(lane>>4)*4+j
  const float sa = s_act[0];
#pragma unroll
  for (int n = 0; n < 4; ++n) {
    const int col = tileN + wc * 64 + n * 16 + l15;
    const float sc = sa * w_scale[col];
    const float bs = bias[col];
#pragma unroll
    for (int m = 0; m < 8; ++m) {
      const int rbase = tileM + wr * 128 + m * 16 + lhi * 4;
#pragma unroll
      for (int j = 0; j < 4; ++j)
        C[(size_t)(rbase + j) * DIM + col] = (float)acc[m][n][j] * sc + bs;
    }
  }
}

// ---------------- launch ----------------
extern "C" void kernel_launch(void* const* d_in, const int* in_sizes, int n_in,
                              void* d_out, int out_size, void* d_ws, size_t ws_size,
                              hipStream_t stream) {
  const float* x    = (const float*)d_in[0];
  const float* w    = (const float*)d_in[1];
  const float* bias = (const float*)d_in[2];
  const float* a_s  = (const float*)d_in[3];
  const int*   a_zp = (const int*)d_in[4];
  const float* w_s  = (const float*)d_in[5];
  const int*   w_zp = (const int*)d_in[6];
  float* out = (float*)d_out;

  signed char* a8 = (signed char*)d_ws;
  signed char* b8 = a8 + (size_t)DIM * DIM;

  const int n4 = DIM * DIM / 4;
  quant_act_kernel<<<2048, 256, 0, stream>>>(x, a_s, a_zp, (int*)a8, n4);
  quant_wgt_kernel<<<2048, 256, 0, stream>>>(w, w_s, w_zp, (int*)b8, n4);

  (void)hipFuncSetAttribute((const void*)gemm_i8_8ph,
                            hipFuncAttributeMaxDynamicSharedMemorySize, 131072);
  gemm_i8_8ph<<<256, 512, 131072, stream>>>(a8, b8, a_s, w_s, bias, out);
}

// Round 4
// 94.739 us; speedup vs baseline: 1.0472x; 1.0472x over previous
//
#include <hip/hip_runtime.h>
#include <stdint.h>

typedef int   int4v   __attribute__((ext_vector_type(4)));
typedef float float4v __attribute__((ext_vector_type(4)));

static constexpr int DIM = 4096;          // N = IN = OUT
static constexpr int BM  = 256, BN = 256; // block tile
static constexpr int BK  = 128;           // K-step bytes (2 MFMA k-steps of K=64)
static constexpr int NKT = DIM / BK;      // 32

// ---------------- quantization kernels ----------------
__global__ __launch_bounds__(256) void quant_act_kernel(
    const float* __restrict__ x, const float* __restrict__ s_ptr,
    const int* __restrict__ zp_ptr, int* __restrict__ out, int n4) {
  const float s  = s_ptr[0];
  const int   zp = zp_ptr[0];
  int idx    = blockIdx.x * blockDim.x + threadIdx.x;
  int stride = gridDim.x * blockDim.x;
  for (int i = idx; i < n4; i += stride) {
    float4v v = reinterpret_cast<const float4v*>(x)[i];
    int packed = 0;
#pragma unroll
    for (int j = 0; j < 4; ++j) {
      int q = (int)rintf(v[j] / s) + zp;
      q = min(max(q, 0), 255);
      q -= zp;
      packed |= (q & 255) << (8 * j);
    }
    out[i] = packed;
  }
}

__global__ __launch_bounds__(256) void quant_wgt_kernel(
    const float* __restrict__ w, const float* __restrict__ ws,
    const int* __restrict__ wzp, int* __restrict__ out, int n4) {
  int idx    = blockIdx.x * blockDim.x + threadIdx.x;
  int stride = gridDim.x * blockDim.x;
  for (int i = idx; i < n4; i += stride) {
    const int row = i >> 10;
    const float s = ws[row];
    const int  zp = wzp[row];
    float4v v = reinterpret_cast<const float4v*>(w)[i];
    int packed = 0;
#pragma unroll
    for (int j = 0; j < 4; ++j) {
      int q = (int)rintf(v[j] / s) + zp;
      q = min(max(q, 0), 255);
      q -= zp;
      packed |= (q & 255) << (8 * j);
    }
    out[i] = packed;
  }
}

// ---------------- int8 GEMM: 256^2, 8 waves, software-pipelined, 2 barriers/K-tile ----
// Every ds_read is issued one MFMA-cluster before its consuming MFMA so LDS BW
// overlaps the matrix pipe. Sync points per K-tile:
//   mid barrier   (lgkmcnt(0)): all waves done reading cur -> staging kt+2 into cur is WAR-safe
//   bnd barrier   (vmcnt(8)):   kt+1's 8 stages landed chip-wide -> next-buffer reads RAW-safe

#define MFMA_QUAD(AF, MH, NL)                                                  \
  __builtin_amdgcn_s_setprio(1);                                               \
  _Pragma("unroll") for (int kk = 0; kk < 2; ++kk)                             \
  _Pragma("unroll") for (int m = 0; m < 4; ++m)                                \
  _Pragma("unroll") for (int n = 0; n < 2; ++n)                                \
      acc[(MH)*4 + m][(NL) + n] = __builtin_amdgcn_mfma_i32_16x16x64_i8(       \
          AF[m][kk], bf[(NL) + n][kk], acc[(MH)*4 + m][(NL) + n], 0, 0, 0);    \
  __builtin_amdgcn_s_setprio(0);

__global__ __launch_bounds__(512) void gemm_i8_pipe(
    const signed char* __restrict__ A, const signed char* __restrict__ B,
    const float* __restrict__ s_act, const float* __restrict__ w_scale,
    const float* __restrict__ bias, float* __restrict__ C) {
  extern __shared__ signed char smem[];  // 2 buffers x (A 32K + B 32K) = 128 KiB

  const int tid  = threadIdx.x;
  const int w    = tid >> 6;            // wave 0..7
  const int lane = tid & 63;
  const int wr = w >> 2, wc = w & 3;    // 2 x 4 wave grid; wave tile 128x64
  const int l15 = lane & 15, lhi = lane >> 4;
  const int swk = (l15 & 7) << 4;       // read-side XOR swizzle key ((row&7)<<4)

  const int srow = lane >> 3;                           // staging row within 8-row chunk
  const int scol = ((lane & 7) ^ (lane >> 3)) << 4;     // pre-swizzled global col

  const int tileM = blockIdx.y * BM;
  const int tileN = blockIdx.x * BN;

  auto stageA = [&](int i, int ktn, signed char* aL) {
    const int c = 4 * w + i;
    const size_t g = (size_t)(tileM + c * 8 + srow) * DIM + (size_t)ktn * BK + scol;
    __builtin_amdgcn_global_load_lds(
        (const __attribute__((address_space(1))) void*)(A + g),
        (__attribute__((address_space(3))) void*)(aL + c * 1024), 16, 0, 0);
  };
  auto stageB = [&](int i, int ktn, signed char* bL) {
    const int c = 4 * w + i;
    const size_t g = (size_t)(tileN + c * 8 + srow) * DIM + (size_t)ktn * BK + scol;
    __builtin_amdgcn_global_load_lds(
        (const __attribute__((address_space(1))) void*)(B + g),
        (__attribute__((address_space(3))) void*)(bL + c * 1024), 16, 0, 0);
  };
  auto rdA = [&](const signed char* aL, int mh, int m, int kk) -> int4v {
    const int r = wr * 128 + (mh * 4 + m) * 16 + l15;
    return *(const int4v*)(aL + r * BK + ((kk * 64 + lhi * 16) ^ swk));
  };
  auto rdB = [&](const signed char* bL, int nidx, int kk) -> int4v {
    const int r = wc * 64 + nidx * 16 + l15;
    return *(const int4v*)(bL + r * BK + ((kk * 64 + lhi * 16) ^ swk));
  };

  int4v acc[8][4] = {};
  int4v afLo[4][2];   // A rows wr*128 + 0..63   (m-tiles 0-3)
  int4v afHi[4][2];   // A rows wr*128 + 64..127 (m-tiles 4-7)
  int4v bf[4][2];     // B cols wc*64 + n*16

  // ---- prologue: stage tile 0 -> buf0, tile 1 -> buf1; wait tile 0; preload S1(0)
  {
    signed char* a0 = smem;
    signed char* b0 = smem + 32768;
    signed char* a1 = smem + 65536;
    signed char* b1 = smem + 65536 + 32768;
#pragma unroll
    for (int i = 0; i < 4; ++i) { stageA(i, 0, a0); stageB(i, 0, b0); }
#pragma unroll
    for (int i = 0; i < 4; ++i) { stageA(i, 1, a1); stageB(i, 1, b1); }
    asm volatile("s_waitcnt vmcnt(8)" ::: "memory");
    __builtin_amdgcn_s_barrier();
#pragma unroll
    for (int m = 0; m < 4; ++m) { afLo[m][0] = rdA(a0, 0, m, 0); afLo[m][1] = rdA(a0, 0, m, 1); }
#pragma unroll
    for (int n = 0; n < 2; ++n) { bf[n][0] = rdB(b0, n, 0); bf[n][1] = rdB(b0, n, 1); }
  }

  for (int kt = 0; kt < NKT; ++kt) {
    signed char* aL = smem + (kt & 1) * 65536;
    signed char* bL = aL + 32768;
    signed char* aN = smem + ((kt + 1) & 1) * 65536;
    signed char* bN = aN + 32768;

    // ---- A: issue S2 (B n2..3) from cur; MFMA quadrant (mh0 x n01) on S1
#pragma unroll
    for (int n = 2; n < 4; ++n) { bf[n][0] = rdB(bL, n, 0); bf[n][1] = rdB(bL, n, 1); }
    MFMA_QUAD(afLo, 0, 0)

    // ---- B: issue S3 (A mh1) from cur; MFMA quadrant (mh0 x n23)
#pragma unroll
    for (int m = 0; m < 4; ++m) { afHi[m][0] = rdA(aL, 1, m, 0); afHi[m][1] = rdA(aL, 1, m, 1); }
    MFMA_QUAD(afLo, 0, 2)
    asm volatile("s_waitcnt lgkmcnt(0)" ::: "memory");  // all own cur-reads complete
    __builtin_amdgcn_s_barrier();                       // mid: cur safe to overwrite

    // ---- C: stage kt+2 -> cur (hidden under MFMA); MFMA quadrant (mh1 x n01)
    if (kt + 2 < NKT) {
#pragma unroll
      for (int i = 0; i < 4; ++i) { stageA(i, kt + 2, aL); stageB(i, kt + 2, bL); }
    }
    MFMA_QUAD(afHi, 1, 0)
    if (kt + 2 < NKT) {
      asm volatile("s_waitcnt vmcnt(8)" ::: "memory");  // kt+1 landed; kt+2 in flight
    } else {
      asm volatile("s_waitcnt vmcnt(0)" ::: "memory");  // tail drain
    }
    __builtin_amdgcn_s_barrier();                       // bnd: next buffer ready chip-wide

    // ---- D: issue S1(kt+1) from next buffer (hidden under last quadrant); MFMA (mh1 x n23)
    if (kt + 1 < NKT) {
#pragma unroll
      for (int m = 0; m < 4; ++m) { afLo[m][0] = rdA(aN, 0, m, 0); afLo[m][1] = rdA(aN, 0, m, 1); }
#pragma unroll
      for (int n = 0; n < 2; ++n) { bf[n][0] = rdB(bN, n, 0); bf[n][1] = rdB(bN, n, 1); }
    }
    MFMA_QUAD(afHi, 1, 2)
  }

  // ---- epilogue: C/D layout col=lane&15, row=(lane>>4)*4+j
  const float sa = s_act[0];
#pragma unroll
  for (int n = 0; n < 4; ++n) {
    const int col = tileN + wc * 64 + n * 16 + l15;
    const float sc = sa * w_scale[col];
    const float bs = bias[col];
#pragma unroll
    for (int m = 0; m < 8; ++m) {
      const int rbase = tileM + wr * 128 + m * 16 + lhi * 4;
#pragma unroll
      for (int j = 0; j < 4; ++j)
        C[(size_t)(rbase + j) * DIM + col] = (float)acc[m][n][j] * sc + bs;
    }
  }
}

// ---------------- launch ----------------
extern "C" void kernel_launch(void* const* d_in, const int* in_sizes, int n_in,
                              void* d_out, int out_size, void* d_ws, size_t ws_size,
                              hipStream_t stream) {
  const float* x    = (const float*)d_in[0];
  const float* w    = (const float*)d_in[1];
  const float* bias = (const float*)d_in[2];
  const float* a_s  = (const float*)d_in[3];
  const int*   a_zp = (const int*)d_in[4];
  const float* w_s  = (const float*)d_in[5];
  const int*   w_zp = (const int*)d_in[6];
  float* out = (float*)d_out;

  signed char* a8 = (signed char*)d_ws;
  signed char* b8 = a8 + (size_t)DIM * DIM;

  const int n4 = DIM * DIM / 4;
  quant_act_kernel<<<2048, 256, 0, stream>>>(x, a_s, a_zp, (int*)a8, n4);
  quant_wgt_kernel<<<2048, 256, 0, stream>>>(w, w_s, w_zp, (int*)b8, n4);

  (void)hipFuncSetAttribute((const void*)gemm_i8_pipe,
                            hipFuncAttributeMaxDynamicSharedMemorySize, 131072);
  dim3 grid(DIM / BN, DIM / BM);  // 16 x 16
  gemm_i8_pipe<<<grid, 512, 131072, stream>>>(a8, b8, a_s, w_s, bias, out);
}